// Round 6
// baseline (324.003 us; speedup 1.0000x reference)
//
#include <hip/hip_runtime.h>
#include <math.h>

#define LSEQ 2048
#define KNB 64
#define BATCH 8
#define MRBF 7
#define NPAIRS (BATCH*LSEQ*KNB)
#define NTILES (NPAIRS/128)
#define BSCALE (255.0f/144.0f)

typedef __attribute__((ext_vector_type(8))) short short8;
typedef __attribute__((ext_vector_type(4))) float floatx4;

// RNE float->bf16 (cold path: weight setup)
__device__ __forceinline__ unsigned short f2bf(float f) {
    unsigned u = __float_as_uint(f);
    u += 0x7fffu + ((u >> 16) & 1u);
    return (unsigned short)(u >> 16);
}
// packed round-half-up bf16x2, 3 ops via v_perm (r4/r5-proven)
__device__ __forceinline__ unsigned pkbf(float a, float b) {
    return __builtin_amdgcn_perm(__float_as_uint(b) + 0x8000u,
                                 __float_as_uint(a) + 0x8000u, 0x07060302u);
}

// ---------------------------------------------------------------------------
// Kernel 1: exact top-K=64 per row; 8 rows/block, all state in registers.
// One distance pass -> packed byte keys in registers + in-cutoff histogram;
// scan; pass 2 compares register keys (no recompute except rare boundary).
// key 0..254 = in-cutoff (d2<144, exact-monotone), 255 = beyond cutoff
// (contributes exactly 0 via smoothstep -> arbitrary fill set).
// ---------------------------------------------------------------------------
__global__ __launch_bounds__(256) void topk_kernel(
    const float* __restrict__ R, int* __restrict__ nbr)
{
    __shared__ unsigned hist[8*256];
    __shared__ float cand_d2[8][128];
    __shared__ int   cand_j[8][128];
    __shared__ int s_B[8], s_need[8], outPos[8], candCnt[8], fillCnt[8];

    const int tid = threadIdx.x;
    const int lane = tid & 63;
    const int wv = tid >> 6;
    const int b  = blockIdx.x >> 8;
    const int i0 = (blockIdx.x & 255) << 3;
    const float* Rb = R + b*LSEQ*3;

    #pragma unroll
    for (int u = 0; u < 8; u++) hist[tid + (u<<8)] = 0u;
    if (tid < 8) { outPos[tid] = 0; candCnt[tid] = 0; fillCnt[tid] = 0; }

    float cx[8], cy[8], cz[8];
    #pragma unroll
    for (int c = 0; c < 8; c++) {
        cx[c] = Rb[(i0+c)*3+0]; cy[c] = Rb[(i0+c)*3+1]; cz[c] = Rb[(i0+c)*3+2];
    }
    float jx[8], jy[8], jz[8];
    #pragma unroll
    for (int u = 0; u < 8; u++) {
        int j = tid + (u<<8);
        jx[u] = Rb[3*j]; jy[u] = Rb[3*j+1]; jz[u] = Rb[3*j+2];
    }
    __syncthreads();

    // pass 1: keys to registers (4 per dword), in-cutoff histogram
    unsigned keyw[16];
    #pragma unroll
    for (int u = 0; u < 8; u++) {
        int dj = tid + (u<<8) - i0;
        unsigned k0 = 0u, k1 = 0u;
        #pragma unroll
        for (int c = 0; c < 8; c++) {
            float dx = cx[c]-jx[u], dy = cy[c]-jy[u], dz = cz[c]-jz[u];
            float d2 = dx*dx + dy*dy + dz*dz;
            int dd = dj - c; dd = dd < 0 ? -dd : dd;
            unsigned key = 255u;
            if (d2 < 144.0f) {
                key = (unsigned)(d2*BSCALE);               // 0..254 exact-monotone
                if (dd > 3) atomicAdd(&hist[(c<<8)+key], 1u);
            }
            if (c < 4) k0 |= key << (8*c); else k1 |= key << (8*(c-4));
        }
        keyw[2*u] = k0; keyw[2*u+1] = k1;
    }
    __syncthreads();

    // scan: wave wv handles rows wv, wv+4; lane covers bins 4*lane..+3
    #pragma unroll
    for (int rr = wv; rr < 8; rr += 4) {
        unsigned h4[4]; unsigned s = 0;
        #pragma unroll
        for (int v = 0; v < 4; v++) { h4[v] = hist[(rr<<8) + lane*4 + v]; s += h4[v]; }
        unsigned inc = s;
        #pragma unroll
        for (int off = 1; off < 64; off <<= 1) {
            unsigned n = __shfl_up(inc, off, 64);
            if (lane >= off) inc += n;
        }
        unsigned tot = __shfl(inc, 63, 64);
        unsigned excl = inc - s;
        if (tot < 64u) {
            if (lane == 0) { s_B[rr] = 255; s_need[rr] = 64 - (int)tot; }
        } else if (excl < 64u && 64u <= inc) {
            unsigned cc = excl;
            #pragma unroll
            for (int v = 0; v < 4; v++) {
                if (cc < 64u && 64u <= cc + h4[v]) { s_B[rr] = lane*4+v; s_need[rr] = 64 - (int)cc; }
                cc += h4[v];
            }
        }
    }
    __syncthreads();

    // pass 2: register-key compare; winners scatter, boundary -> exact cand
    #pragma unroll
    for (int u = 0; u < 8; u++) {
        int j = tid + (u<<8);
        int dj = j - i0;
        #pragma unroll
        for (int c = 0; c < 8; c++) {
            int dd = dj - c; dd = dd < 0 ? -dd : dd;
            if (dd <= 3) continue;
            int key = (int)((keyw[2*u + (c>>2)] >> (8*(c&3))) & 255u);
            int B = s_B[c];
            int obase = (b*LSEQ + i0 + c)*KNB;
            if (key < B) {
                int pos = atomicAdd(&outPos[c], 1);
                nbr[obase + pos] = j;
            } else if (key == B) {
                if (B == 255) {
                    // <64 inside cutoff: fill with beyond-cutoff pairs (exact 0)
                    int t = atomicAdd(&fillCnt[c], 1);
                    if (t < s_need[c]) {
                        int pos = atomicAdd(&outPos[c], 1);
                        nbr[obase + pos] = j;
                    }
                } else {
                    float dx = cx[c]-jx[u], dy = cy[c]-jy[u], dz = cz[c]-jz[u];
                    float d2 = dx*dx + dy*dy + dz*dz;
                    int cc = atomicAdd(&candCnt[c], 1);
                    if (cc < 128) { cand_d2[c][cc] = d2; cand_j[c][cc] = j; }
                }
            }
        }
    }
    __syncthreads();

    // boundary bin: exact (d2, j) rank
    for (int rr = wv; rr < 8; rr += 4) {
        int B = s_B[rr];
        if (B == 255) continue;
        int c = candCnt[rr]; if (c > 128) c = 128;
        int need = s_need[rr];
        int obase = (b*LSEQ + i0 + rr)*KNB;
        for (int ci = lane; ci < c; ci += 64) {
            float dv = cand_d2[rr][ci]; int jv = cand_j[rr][ci];
            int rank = 0;
            for (int x = 0; x < c; x++) {
                float dx2 = cand_d2[rr][x]; int jx2 = cand_j[rr][x];
                rank += (dx2 < dv) || (dx2 == dv && jx2 < jv);
            }
            if (rank < need) {
                int pos = atomicAdd(&outPos[rr], 1);
                nbr[obase + pos] = jv;
            }
        }
    }
}

// ---------------------------------------------------------------------------
// Kernel 2: pair MLP via bf16 MFMA (r5 structure, de-bugged):
//  - XOR-swizzled LDS (chunk16B ^= row&7): conflict-free b128 reads/b64 writes
//  - H2 buffer aliases X (X dead after GEMM1) -> 64 KB LDS, 2 blocks/CU
//  - prefetch manually inlined as scalar float4s (NO array params -> no alloca
//    -> no scratch; r5's 94 MB WRITE_SIZE was spilled prefetch state)
//  - r carried in a register, delivered to GEMM3 via intra-wave shuffle
// Fragment layouts (r2/r4/r5 HW-verified, absmax=0):
//  A[m][k]: m=lane&15, k=quad*8+j | B[k][n]: n=lane&15, k=quad*8+j
//  D[r][c]: r=quad*4+reg, c=lane&15
// ---------------------------------------------------------------------------
__global__ __launch_bounds__(256, 2) void mlp_mfma_kernel(
    const float* __restrict__ R, const int* __restrict__ seq,
    const float* __restrict__ emb,
    const float* __restrict__ W1, const float* __restrict__ b1,
    const float* __restrict__ W2, const float* __restrict__ b2,
    const float* __restrict__ W3, const float* __restrict__ b3,
    const float* __restrict__ centers, const float* __restrict__ widths,
    const int* __restrict__ nbr, float* __restrict__ out)
{
    __shared__ __align__(16) unsigned short lds[32768];  // 64 KB
    unsigned short* H1s = lds;            // [pair 0..127][neuron 0..127], 32 KB
    unsigned short* Xs  = lds + 16384;    // [pair][feat 0..63], 16 KB (dead after GEMM1)
    unsigned short* H2s = lds + 16384;    // [pair][neuron], 32 KB (aliases Xs)
    __shared__ float bacc[BATCH];

    const int tid  = threadIdx.x;
    const int lane = tid & 63;
    const int wv   = tid >> 6;
    const int l15  = lane & 15;
    const int q    = lane >> 4;

    // ---- persistent A-operand weight fragments (wave-sharded neurons) ----
    short8 w1f[2][2], w2f[2][4], w3f[4];
    float b1v[2][4], b2v[2][4];
    #pragma unroll
    for (int mtl = 0; mtl < 2; mtl++) {
        int m = (2*wv + mtl)*16 + l15;
        #pragma unroll
        for (int d = 0; d < 4; d++) {
            b1v[mtl][d] = b1[(2*wv + mtl)*16 + q*4 + d];
            b2v[mtl][d] = b2[(2*wv + mtl)*16 + q*4 + d];
        }
        #pragma unroll
        for (int kt = 0; kt < 2; kt++)
            #pragma unroll
            for (int jj = 0; jj < 8; jj++) {
                int k = kt*32 + q*8 + jj;
                w1f[mtl][kt][jj] = (short)((k < 48) ? f2bf(W1[k*128 + m]) : 0);
            }
        #pragma unroll
        for (int kt = 0; kt < 4; kt++)
            #pragma unroll
            for (int jj = 0; jj < 8; jj++) {
                int k = kt*32 + q*8 + jj;
                w2f[mtl][kt][jj] = (short)f2bf(W2[k*128 + m]);
            }
    }
    #pragma unroll
    for (int kt = 0; kt < 4; kt++)
        #pragma unroll
        for (int jj = 0; jj < 8; jj++) {
            int k = kt*32 + q*8 + jj;
            w3f[kt][jj] = (short)((l15 < MRBF) ? f2bf(W3[k*MRBF + l15]) : 0);
        }
    float b3C[4], cen[4], i2w[4];
    #pragma unroll
    for (int d = 0; d < 4; d++) {
        int rb = q*4 + d;
        bool ok = rb < MRBF;
        b3C[d] = ok ? b3[rb] : 0.f;
        cen[d] = ok ? centers[rb] : 0.f;
        float wd = ok ? widths[rb] : 1.f;
        i2w[d] = 0.5f / (wd*wd);
    }
    if (tid < BATCH) bacc[tid] = 0.f;

    const int pl = tid >> 1, half = tid & 1;
    const int s7p = pl & 7;

    // ---- initial prefetch: named scalars only (no arrays -> no alloca) ----
    float4 eA0, eA1, eB0, eB1;
    float rA0, rA1, rA2, rB0, rB1, rB2;
    {
        int p  = blockIdx.x*128 + pl;
        int bi = p >> 6, bb = p >> 17;
        int jn = nbr[p];
        int rowj = (bb << 11) + jn;
        int si = seq[bi], sj = seq[rowj];
        const float4* ei = (const float4*)(emb + si*16 + half*8);
        const float4* ej = (const float4*)(emb + sj*16 + half*8);
        eA0 = ei[0]; eA1 = ei[1]; eB0 = ej[0]; eB1 = ej[1];
        rA0 = R[bi*3+0];   rA1 = R[bi*3+1];   rA2 = R[bi*3+2];
        rB0 = R[rowj*3+0]; rB1 = R[rowj*3+1]; rB2 = R[rowj*3+2];
    }

    float rloc = 0.f;
    for (int tile = blockIdx.x; tile < NTILES; tile += gridDim.x) {
        __syncthreads();   // prior tile's H2 readers done (X aliases H2)

        // ---- X write from prefetched scalars (swizzled chunks) ----
        {
            int rb = pl*64;
            uint4 vA = make_uint4(pkbf(eA0.x,eA0.y), pkbf(eA0.z,eA0.w),
                                  pkbf(eA1.x,eA1.y), pkbf(eA1.z,eA1.w));
            uint4 vB = make_uint4(pkbf(eB0.x,eB0.y), pkbf(eB0.z,eB0.w),
                                  pkbf(eB1.x,eB1.y), pkbf(eB1.z,eB1.w));
            uint4 vP = make_uint4(pkbf(eA0.x*eB0.x, eA0.y*eB0.y),
                                  pkbf(eA0.z*eB0.z, eA0.w*eB0.w),
                                  pkbf(eA1.x*eB1.x, eA1.y*eB1.y),
                                  pkbf(eA1.z*eB1.z, eA1.w*eB1.w));
            *(uint4*)&Xs[rb + (((0|half)^s7p)<<3)] = vA;
            *(uint4*)&Xs[rb + (((2|half)^s7p)<<3)] = vB;
            *(uint4*)&Xs[rb + (((4|half)^s7p)<<3)] = vP;
            *(uint4*)&Xs[rb + (((6|half)^s7p)<<3)] = make_uint4(0u,0u,0u,0u);
            if (!half) {
                float dx = rA0-rB0, dy = rA1-rB1, dz = rA2-rB2;
                rloc = sqrtf(dx*dx + dy*dy + dz*dz + 1e-12f);
            }
        }
        __syncthreads();

        // ---- prefetch next tile (inline, overlaps GEMMs) ----
        int tn = tile + gridDim.x;
        if (tn < NTILES) {
            int p  = tn*128 + pl;
            int bi = p >> 6, bb = p >> 17;
            int jn = nbr[p];
            int rowj = (bb << 11) + jn;
            int si = seq[bi], sj = seq[rowj];
            const float4* ei = (const float4*)(emb + si*16 + half*8);
            const float4* ej = (const float4*)(emb + sj*16 + half*8);
            eA0 = ei[0]; eA1 = ei[1]; eB0 = ej[0]; eB1 = ej[1];
            rA0 = R[bi*3+0];   rA1 = R[bi*3+1];   rA2 = R[bi*3+2];
            rB0 = R[rowj*3+0]; rB1 = R[rowj*3+1]; rB2 = R[rowj*3+2];
        }

        // ---- GEMM1: H1 = relu(W1^T X^T + b1) ----
        #pragma unroll
        for (int nt = 0; nt < 8; nt++) {
            int row = nt*16 + l15;
            int s7 = l15 & 7;
            const unsigned short* xr = Xs + row*64;
            short8 x0 = *(const short8*)&xr[(( q    ^ s7) << 3)];
            short8 x1 = *(const short8*)&xr[(((4|q) ^ s7) << 3)];
            #pragma unroll
            for (int mtl = 0; mtl < 2; mtl++) {
                floatx4 acc = {b1v[mtl][0], b1v[mtl][1], b1v[mtl][2], b1v[mtl][3]};
                acc = __builtin_amdgcn_mfma_f32_16x16x32_bf16(w1f[mtl][0], x0, acc, 0, 0, 0);
                acc = __builtin_amdgcn_mfma_f32_16x16x32_bf16(w1f[mtl][1], x1, acc, 0, 0, 0);
                int chnk = (((2*wv + mtl)*2 + (q>>1)) ^ s7);
                *(uint2*)&H1s[row*128 + (chnk<<3) + ((q&1)<<2)] =
                    make_uint2(pkbf(fmaxf(acc[0],0.f), fmaxf(acc[1],0.f)),
                               pkbf(fmaxf(acc[2],0.f), fmaxf(acc[3],0.f)));
            }
        }
        __syncthreads();

        // ---- GEMM2: H2 = relu(W2^T H1^T + b2); H2 overwrites dead X ----
        #pragma unroll
        for (int nt = 0; nt < 8; nt++) {
            int row = nt*16 + l15;
            int s7 = l15 & 7;
            const unsigned short* hr = H1s + row*128;
            short8 hf0 = *(const short8*)&hr[(( q     ^ s7) << 3)];
            short8 hf1 = *(const short8*)&hr[((( 4|q) ^ s7) << 3)];
            short8 hf2 = *(const short8*)&hr[((( 8|q) ^ s7) << 3)];
            short8 hf3 = *(const short8*)&hr[(((12|q) ^ s7) << 3)];
            #pragma unroll
            for (int mtl = 0; mtl < 2; mtl++) {
                floatx4 acc = {b2v[mtl][0], b2v[mtl][1], b2v[mtl][2], b2v[mtl][3]};
                acc = __builtin_amdgcn_mfma_f32_16x16x32_bf16(w2f[mtl][0], hf0, acc, 0, 0, 0);
                acc = __builtin_amdgcn_mfma_f32_16x16x32_bf16(w2f[mtl][1], hf1, acc, 0, 0, 0);
                acc = __builtin_amdgcn_mfma_f32_16x16x32_bf16(w2f[mtl][2], hf2, acc, 0, 0, 0);
                acc = __builtin_amdgcn_mfma_f32_16x16x32_bf16(w2f[mtl][3], hf3, acc, 0, 0, 0);
                int chnk = (((2*wv + mtl)*2 + (q>>1)) ^ s7);
                *(uint2*)&H2s[row*128 + (chnk<<3) + ((q&1)<<2)] =
                    make_uint2(pkbf(fmaxf(acc[0],0.f), fmaxf(acc[1],0.f)),
                               pkbf(fmaxf(acc[2],0.f), fmaxf(acc[3],0.f)));
            }
        }
        __syncthreads();

        // ---- GEMM3 (W3^T H2^T) + epilogue; wave owns pair-tiles 2wv,2wv+1 ----
        float esum = 0.f;
        #pragma unroll
        for (int ntl = 0; ntl < 2; ntl++) {
            int nt = 2*wv + ntl;
            int row = nt*16 + l15;
            int s7 = l15 & 7;
            const unsigned short* hr = H2s + row*128;
            floatx4 a3 = {b3C[0], b3C[1], b3C[2], b3C[3]};
            #pragma unroll
            for (int kt = 0; kt < 4; kt++) {
                short8 hf = *(const short8*)&hr[((((kt<<2)|q) ^ s7) << 3)];
                a3 = __builtin_amdgcn_mfma_f32_16x16x32_bf16(w3f[kt], hf, a3, 0, 0, 0);
            }
            // pair p=32wv+16ntl+l15 had r computed by tid 2p -> lane 32ntl+2l15
            float rr = __shfl(rloc, (ntl<<5) + 2*l15, 64);
            if (rr < 12.0f) {   // uniform within each xor16/32 shuffle group
                float att = 0.f;
                #pragma unroll
                for (int d = 0; d < 4; d++) {
                    if (q*4 + d < MRBF) {
                        float x = a3[d];
                        float sp = fmaxf(x, 0.f) + __logf(1.f + __expf(-fabsf(x)));
                        float df = rr - cen[d];
                        att += sp * __expf(-df*df*i2w[d]);
                    }
                }
                att += __shfl_xor(att, 16, 64);
                att += __shfl_xor(att, 32, 64);
                float t = fminf(fmaxf((rr - 10.f)*0.5f, 0.f), 1.f);
                float sw = 1.f - t*t*(3.f - 2.f*t);
                esum -= att * sw;   // 4x quad-replicated; x0.25 at flush
            }
        }
        #pragma unroll
        for (int off = 1; off < 64; off <<= 1)
            esum += __shfl_xor(esum, off, 64);
        if (lane == 0) atomicAdd(&bacc[tile >> 10], esum * 0.25f);
    }
    __syncthreads();
    if (tid < BATCH) atomicAdd(&out[tid], bacc[tid]);
}

// ---------------------------------------------------------------------------
extern "C" void kernel_launch(void* const* d_in, const int* in_sizes, int n_in,
                              void* d_out, int out_size, void* d_ws, size_t ws_size,
                              hipStream_t stream) {
    const float* R       = (const float*)d_in[0];
    const int*   seq     = (const int*)  d_in[1];
    const float* emb     = (const float*)d_in[2];
    const float* W1      = (const float*)d_in[3];
    const float* b1      = (const float*)d_in[4];
    const float* W2      = (const float*)d_in[5];
    const float* b2      = (const float*)d_in[6];
    const float* W3      = (const float*)d_in[7];
    const float* b3      = (const float*)d_in[8];
    const float* centers = (const float*)d_in[9];
    const float* widths  = (const float*)d_in[10];
    float* out = (float*)d_out;
    int*   nbr = (int*)d_ws;   // NPAIRS ints = 4 MiB

    hipMemsetAsync(d_out, 0, out_size * sizeof(float), stream);

    topk_kernel<<<2048, 256, 0, stream>>>(R, nbr);
    mlp_mfma_kernel<<<512, 256, 0, stream>>>(R, seq, emb, W1, b1, W2, b2, W3, b3,
                                             centers, widths, nbr, out);
}

// Round 7
// 253.726 us; speedup vs baseline: 1.2770x; 1.2770x over previous
//
#include <hip/hip_runtime.h>
#include <math.h>

#define LSEQ 2048
#define KNB 64
#define BATCH 8
#define MRBF 7
#define NTILES 8192               // 2 rows per tile, 128 pairs
#define NBLOCKS 512
#define BSCALE (255.0f/144.0f)

typedef __attribute__((ext_vector_type(8))) short short8;
typedef __attribute__((ext_vector_type(4))) float floatx4;

// RNE float->bf16 (cold path: weight setup)
__device__ __forceinline__ unsigned short f2bf(float f) {
    unsigned u = __float_as_uint(f);
    u += 0x7fffu + ((u >> 16) & 1u);
    return (unsigned short)(u >> 16);
}
// packed round-half-up bf16x2, 3 ops via v_perm (r4/r5/r6-proven)
__device__ __forceinline__ unsigned pkbf(float a, float b) {
    return __builtin_amdgcn_perm(__float_as_uint(b) + 0x8000u,
                                 __float_as_uint(a) + 0x8000u, 0x07060302u);
}

// ---------------------------------------------------------------------------
// Fused kernel: per 128-pair tile (= 2 rows), run exact top-K=64 select for
// the 2 rows (r6-verified histogram algorithm), winners -> LDS nbrL, then the
// r6 MFMA MLP (swizzled LDS, H2 aliases X). Fusion hides topk's load/atomic
// latency under co-resident blocks' MFMA phases and kills the 4 MB nbr
// round-trip + the standalone dispatch (153 us of ~80% stall in r6).
// Topk scratch aliases H1s: H1s is only live GEMM1->GEMM2 (last read fenced
// by the GEMM2-end barrier), topk phase runs before GEMM1.
// Fragment layouts (r2/r4/r5/r6 HW-verified, absmax=0):
//  A[m][k]: m=lane&15, k=quad*8+j | B[k][n]: n=lane&15, k=quad*8+j
//  D[r][c]: r=quad*4+reg, c=lane&15
// ---------------------------------------------------------------------------
__global__ __launch_bounds__(256, 2) void fused_kernel(
    const float* __restrict__ R, const int* __restrict__ seq,
    const float* __restrict__ emb,
    const float* __restrict__ W1, const float* __restrict__ b1,
    const float* __restrict__ W2, const float* __restrict__ b2,
    const float* __restrict__ W3, const float* __restrict__ b3,
    const float* __restrict__ centers, const float* __restrict__ widths,
    float* __restrict__ out)
{
    __shared__ __align__(16) unsigned short lds[32768];  // 64 KB
    unsigned short* H1s = lds;            // bytes [0,32768): H1, live GEMM1->GEMM2
    unsigned short* Xs  = lds + 16384;    // bytes [32768,49152): X, dead after GEMM1
    unsigned short* H2s = lds + 16384;    // bytes [32768,65536): H2 (aliases X)
    // topk scratch aliases H1s (live only in the topk phase):
    int*      nbrL    = (int*)lds;                     // 128 ints  [0,512)
    unsigned* hist    = (unsigned*)((char*)lds + 512); // 512 u32   [512,2560)
    float*    cand_d2 = (float*)((char*)lds + 2560);   // 2x128 f32 [2560,3584)
    int*      cand_j  = (int*)((char*)lds + 3584);     // 2x128 int [3584,4608)
    int*      tctr    = (int*)((char*)lds + 4608);     // 10 ints
    int* sB    = tctr + 0;
    int* sNeed = tctr + 2;
    int* oPos  = tctr + 4;
    int* cCnt  = tctr + 6;
    int* fCnt  = tctr + 8;
    __shared__ float bacc[BATCH];

    const int tid  = threadIdx.x;
    const int lane = tid & 63;
    const int wv   = tid >> 6;
    const int l15  = lane & 15;
    const int q    = lane >> 4;

    // ---- persistent A-operand weight fragments (wave-sharded neurons) ----
    short8 w1f[2][2], w2f[2][4], w3f[4];
    float b1v[2][4], b2v[2][4];
    #pragma unroll
    for (int mtl = 0; mtl < 2; mtl++) {
        int m = (2*wv + mtl)*16 + l15;
        #pragma unroll
        for (int d = 0; d < 4; d++) {
            b1v[mtl][d] = b1[(2*wv + mtl)*16 + q*4 + d];
            b2v[mtl][d] = b2[(2*wv + mtl)*16 + q*4 + d];
        }
        #pragma unroll
        for (int kt = 0; kt < 2; kt++)
            #pragma unroll
            for (int jj = 0; jj < 8; jj++) {
                int k = kt*32 + q*8 + jj;
                w1f[mtl][kt][jj] = (short)((k < 48) ? f2bf(W1[k*128 + m]) : 0);
            }
        #pragma unroll
        for (int kt = 0; kt < 4; kt++)
            #pragma unroll
            for (int jj = 0; jj < 8; jj++) {
                int k = kt*32 + q*8 + jj;
                w2f[mtl][kt][jj] = (short)f2bf(W2[k*128 + m]);
            }
    }
    #pragma unroll
    for (int kt = 0; kt < 4; kt++)
        #pragma unroll
        for (int jj = 0; jj < 8; jj++) {
            int k = kt*32 + q*8 + jj;
            w3f[kt][jj] = (short)((l15 < MRBF) ? f2bf(W3[k*MRBF + l15]) : 0);
        }
    float b3C[4], cen[4], i2w[4];
    #pragma unroll
    for (int d = 0; d < 4; d++) {
        int rb = q*4 + d;
        bool ok = rb < MRBF;
        b3C[d] = ok ? b3[rb] : 0.f;
        cen[d] = ok ? centers[rb] : 0.f;
        float wd = ok ? widths[rb] : 1.f;
        i2w[d] = 0.5f / (wd*wd);
    }
    if (tid < BATCH) bacc[tid] = 0.f;

    const int pl = tid >> 1, half = tid & 1;
    const int s7p = pl & 7;
    float rloc = 0.f;

    for (int tile = blockIdx.x; tile < NTILES; tile += NBLOCKS) {
        const int b     = tile >> 10;            // 1024 tiles per batch
        const int ibase = (tile & 1023) << 1;    // first row (within batch)
        const float* Rb = R + ((b << 11) * 3);

        __syncthreads();   // prior tile: H2s readers done, H1s region free

        // ================= TOPK PHASE (2 rows) =================
        hist[tid] = 0u; hist[tid + 256] = 0u;
        if (tid < 2) { oPos[tid] = 0; cCnt[tid] = 0; fCnt[tid] = 0; }

        // 8 consecutive candidate points per thread, coalesced float4 loads
        float px[8], py[8], pz[8];
        {
            const float4* rp = (const float4*)(Rb + tid*24);
            float4 f0=rp[0], f1=rp[1], f2=rp[2], f3=rp[3], f4=rp[4], f5=rp[5];
            px[0]=f0.x; py[0]=f0.y; pz[0]=f0.z;
            px[1]=f0.w; py[1]=f1.x; pz[1]=f1.y;
            px[2]=f1.z; py[2]=f1.w; pz[2]=f2.x;
            px[3]=f2.y; py[3]=f2.z; pz[3]=f2.w;
            px[4]=f3.x; py[4]=f3.y; pz[4]=f3.z;
            px[5]=f3.w; py[5]=f4.x; pz[5]=f4.y;
            px[6]=f4.z; py[6]=f4.w; pz[6]=f5.x;
            px[7]=f5.y; py[7]=f5.z; pz[7]=f5.w;
        }
        float cx0 = Rb[3*ibase+0], cy0 = Rb[3*ibase+1], cz0 = Rb[3*ibase+2];
        float cx1 = Rb[3*ibase+3], cy1 = Rb[3*ibase+4], cz1 = Rb[3*ibase+5];
        __syncthreads();   // hist zero visible

        // pass 1: d2 to registers, in-cutoff histogram
        // bonded -> d2=1e30 (excluded from cutoff AND fill); key 0..254 exact-
        // monotone in d2; beyond cutoff contributes exactly 0 (smoothstep)
        float d2r[2][8];
        #pragma unroll
        for (int u = 0; u < 8; u++) {
            int j = tid*8 + u;
            #pragma unroll
            for (int c = 0; c < 2; c++) {
                float dx = (c ? cx1 : cx0) - px[u];
                float dy = (c ? cy1 : cy0) - py[u];
                float dz = (c ? cz1 : cz0) - pz[u];
                float d2 = dx*dx + dy*dy + dz*dz;
                int dd = j - (ibase + c); dd = dd < 0 ? -dd : dd;
                if (dd <= 3) d2 = 1e30f;
                d2r[c][u] = d2;
                if (d2 < 144.0f)
                    atomicAdd(&hist[(c<<8) + (int)(d2*BSCALE)], 1u);
            }
        }
        __syncthreads();

        // scan: wave 0 -> row 0, wave 1 -> row 1 (r6-verified logic)
        if (wv < 2) {
            unsigned h4[4]; unsigned s = 0;
            #pragma unroll
            for (int v = 0; v < 4; v++) { h4[v] = hist[(wv<<8) + lane*4 + v]; s += h4[v]; }
            unsigned inc = s;
            #pragma unroll
            for (int off = 1; off < 64; off <<= 1) {
                unsigned n = __shfl_up(inc, off, 64);
                if (lane >= off) inc += n;
            }
            unsigned tot = __shfl(inc, 63, 64);
            unsigned excl = inc - s;
            if (tot < 64u) {
                if (lane == 0) { sB[wv] = 255; sNeed[wv] = 64 - (int)tot; }
            } else if (excl < 64u && 64u <= inc) {
                unsigned cc = excl;
                #pragma unroll
                for (int v = 0; v < 4; v++) {
                    if (cc < 64u && 64u <= cc + h4[v]) { sB[wv] = lane*4+v; sNeed[wv] = 64 - (int)cc; }
                    cc += h4[v];
                }
            }
        }
        __syncthreads();

        // pass 2: winners -> nbrL; boundary bin -> exact candidates; far fill
        #pragma unroll
        for (int u = 0; u < 8; u++) {
            int j = tid*8 + u;
            #pragma unroll
            for (int c = 0; c < 2; c++) {
                float d2 = d2r[c][u];
                int B = sB[c];
                if (d2 < 144.0f) {
                    int key = (int)(d2*BSCALE);
                    if (key < B) {
                        int pos = atomicAdd(&oPos[c], 1);
                        nbrL[(c<<6) + pos] = j;
                    } else if (key == B) {
                        int cc = atomicAdd(&cCnt[c], 1);
                        if (cc < 128) { cand_d2[(c<<7)+cc] = d2; cand_j[(c<<7)+cc] = j; }
                    }
                } else if (B == 255 && d2 < 1e29f) {
                    // <64 inside cutoff: fill with beyond-cutoff non-bonded
                    // pairs -- each contributes exactly 0 via the smoothstep
                    int t = atomicAdd(&fCnt[c], 1);
                    if (t < sNeed[c]) {
                        int pos = atomicAdd(&oPos[c], 1);
                        nbrL[(c<<6) + pos] = j;
                    }
                }
            }
        }
        __syncthreads();

        // boundary bin: exact (d2, j) rank; wave 0 -> row 0, wave 1 -> row 1
        if (wv < 2) {
            int B = sB[wv];
            if (B != 255) {
                int cn = cCnt[wv]; if (cn > 128) cn = 128;
                int need = sNeed[wv];
                for (int ci = lane; ci < cn; ci += 64) {
                    float dv = cand_d2[(wv<<7)+ci]; int jv = cand_j[(wv<<7)+ci];
                    int rank = 0;
                    for (int x = 0; x < cn; x++) {
                        float dx2 = cand_d2[(wv<<7)+x]; int jx2 = cand_j[(wv<<7)+x];
                        rank += (dx2 < dv) || (dx2 == dv && jx2 < jv);
                    }
                    if (rank < need) {
                        int pos = atomicAdd(&oPos[wv], 1);
                        nbrL[(wv<<6) + pos] = jv;
                    }
                }
            }
        }
        __syncthreads();   // nbrL complete

        // ================= X BUILD (from LDS nbrL) =================
        {
            int c  = pl >> 6;
            int bi = (b << 11) + ibase + c;
            int j  = nbrL[pl];
            int rowj = (b << 11) + j;
            int si = seq[bi], sj = seq[rowj];
            const float4* ei = (const float4*)(emb + si*16 + half*8);
            const float4* ej = (const float4*)(emb + sj*16 + half*8);
            float4 eA0 = ei[0], eA1 = ei[1], eB0 = ej[0], eB1 = ej[1];
            int rb = pl*64;
            uint4 vA = make_uint4(pkbf(eA0.x,eA0.y), pkbf(eA0.z,eA0.w),
                                  pkbf(eA1.x,eA1.y), pkbf(eA1.z,eA1.w));
            uint4 vB = make_uint4(pkbf(eB0.x,eB0.y), pkbf(eB0.z,eB0.w),
                                  pkbf(eB1.x,eB1.y), pkbf(eB1.z,eB1.w));
            uint4 vP = make_uint4(pkbf(eA0.x*eB0.x, eA0.y*eB0.y),
                                  pkbf(eA0.z*eB0.z, eA0.w*eB0.w),
                                  pkbf(eA1.x*eB1.x, eA1.y*eB1.y),
                                  pkbf(eA1.z*eB1.z, eA1.w*eB1.w));
            *(uint4*)&Xs[rb + (((0|half)^s7p)<<3)] = vA;
            *(uint4*)&Xs[rb + (((2|half)^s7p)<<3)] = vB;
            *(uint4*)&Xs[rb + (((4|half)^s7p)<<3)] = vP;
            *(uint4*)&Xs[rb + (((6|half)^s7p)<<3)] = make_uint4(0u,0u,0u,0u);
            if (!half) {
                float dx = R[bi*3+0]-R[rowj*3+0];
                float dy = R[bi*3+1]-R[rowj*3+1];
                float dz = R[bi*3+2]-R[rowj*3+2];
                rloc = sqrtf(dx*dx + dy*dy + dz*dz + 1e-12f);
            }
        }
        __syncthreads();   // X ready; topk scratch (H1s region) now dead

        // ================= GEMM1: H1 = relu(W1^T X^T + b1) =================
        #pragma unroll
        for (int nt = 0; nt < 8; nt++) {
            int row = nt*16 + l15;
            int s7 = l15 & 7;
            const unsigned short* xr = Xs + row*64;
            short8 x0 = *(const short8*)&xr[(( q    ^ s7) << 3)];
            short8 x1 = *(const short8*)&xr[(((4|q) ^ s7) << 3)];
            #pragma unroll
            for (int mtl = 0; mtl < 2; mtl++) {
                floatx4 acc = {b1v[mtl][0], b1v[mtl][1], b1v[mtl][2], b1v[mtl][3]};
                acc = __builtin_amdgcn_mfma_f32_16x16x32_bf16(w1f[mtl][0], x0, acc, 0, 0, 0);
                acc = __builtin_amdgcn_mfma_f32_16x16x32_bf16(w1f[mtl][1], x1, acc, 0, 0, 0);
                int chnk = (((2*wv + mtl)*2 + (q>>1)) ^ s7);
                *(uint2*)&H1s[row*128 + (chnk<<3) + ((q&1)<<2)] =
                    make_uint2(pkbf(fmaxf(acc[0],0.f), fmaxf(acc[1],0.f)),
                               pkbf(fmaxf(acc[2],0.f), fmaxf(acc[3],0.f)));
            }
        }
        __syncthreads();

        // ======== GEMM2: H2 = relu(W2^T H1^T + b2); overwrites dead X ======
        #pragma unroll
        for (int nt = 0; nt < 8; nt++) {
            int row = nt*16 + l15;
            int s7 = l15 & 7;
            const unsigned short* hr = H1s + row*128;
            short8 hf0 = *(const short8*)&hr[(( q     ^ s7) << 3)];
            short8 hf1 = *(const short8*)&hr[((( 4|q) ^ s7) << 3)];
            short8 hf2 = *(const short8*)&hr[((( 8|q) ^ s7) << 3)];
            short8 hf3 = *(const short8*)&hr[(((12|q) ^ s7) << 3)];
            #pragma unroll
            for (int mtl = 0; mtl < 2; mtl++) {
                floatx4 acc = {b2v[mtl][0], b2v[mtl][1], b2v[mtl][2], b2v[mtl][3]};
                acc = __builtin_amdgcn_mfma_f32_16x16x32_bf16(w2f[mtl][0], hf0, acc, 0, 0, 0);
                acc = __builtin_amdgcn_mfma_f32_16x16x32_bf16(w2f[mtl][1], hf1, acc, 0, 0, 0);
                acc = __builtin_amdgcn_mfma_f32_16x16x32_bf16(w2f[mtl][2], hf2, acc, 0, 0, 0);
                acc = __builtin_amdgcn_mfma_f32_16x16x32_bf16(w2f[mtl][3], hf3, acc, 0, 0, 0);
                int chnk = (((2*wv + mtl)*2 + (q>>1)) ^ s7);
                *(uint2*)&H2s[row*128 + (chnk<<3) + ((q&1)<<2)] =
                    make_uint2(pkbf(fmaxf(acc[0],0.f), fmaxf(acc[1],0.f)),
                               pkbf(fmaxf(acc[2],0.f), fmaxf(acc[3],0.f)));
            }
        }
        __syncthreads();

        // ====== GEMM3 (W3^T H2^T) + epilogue; wave owns pair-tiles 2wv+ ====
        float esum = 0.f;
        #pragma unroll
        for (int ntl = 0; ntl < 2; ntl++) {
            int nt = 2*wv + ntl;
            int row = nt*16 + l15;
            int s7 = l15 & 7;
            const unsigned short* hr = H2s + row*128;
            floatx4 a3 = {b3C[0], b3C[1], b3C[2], b3C[3]};
            #pragma unroll
            for (int kt = 0; kt < 4; kt++) {
                short8 hf = *(const short8*)&hr[((((kt<<2)|q) ^ s7) << 3)];
                a3 = __builtin_amdgcn_mfma_f32_16x16x32_bf16(w3f[kt], hf, a3, 0, 0, 0);
            }
            // pair p = 32wv+16ntl+l15; its r lives in lane 32ntl+2*l15 (r6-verified)
            float rr = __shfl(rloc, (ntl<<5) + 2*l15, 64);
            if (rr < 12.0f) {
                float att = 0.f;
                #pragma unroll
                for (int d = 0; d < 4; d++) {
                    if (q*4 + d < MRBF) {
                        float x = a3[d];
                        float sp = fmaxf(x, 0.f) + __logf(1.f + __expf(-fabsf(x)));
                        float df = rr - cen[d];
                        att += sp * __expf(-df*df*i2w[d]);
                    }
                }
                att += __shfl_xor(att, 16, 64);
                att += __shfl_xor(att, 32, 64);
                float t = fminf(fmaxf((rr - 10.f)*0.5f, 0.f), 1.f);
                float sw = 1.f - t*t*(3.f - 2.f*t);
                esum -= att * sw;   // 4x quad-replicated; x0.25 at flush
            }
        }
        #pragma unroll
        for (int off = 1; off < 64; off <<= 1)
            esum += __shfl_xor(esum, off, 64);
        if (lane == 0) atomicAdd(&bacc[b], esum * 0.25f);
    }
    __syncthreads();
    if (tid < BATCH) atomicAdd(&out[tid], bacc[tid]);
}

// ---------------------------------------------------------------------------
extern "C" void kernel_launch(void* const* d_in, const int* in_sizes, int n_in,
                              void* d_out, int out_size, void* d_ws, size_t ws_size,
                              hipStream_t stream) {
    const float* R       = (const float*)d_in[0];
    const int*   seq     = (const int*)  d_in[1];
    const float* emb     = (const float*)d_in[2];
    const float* W1      = (const float*)d_in[3];
    const float* b1      = (const float*)d_in[4];
    const float* W2      = (const float*)d_in[5];
    const float* b2      = (const float*)d_in[6];
    const float* W3      = (const float*)d_in[7];
    const float* b3      = (const float*)d_in[8];
    const float* centers = (const float*)d_in[9];
    const float* widths  = (const float*)d_in[10];
    float* out = (float*)d_out;

    hipMemsetAsync(d_out, 0, out_size * sizeof(float), stream);

    fused_kernel<<<NBLOCKS, 256, 0, stream>>>(R, seq, emb, W1, b1, W2, b2, W3, b3,
                                              centers, widths, out);
}